// Round 1
// baseline (3712.335 us; speedup 1.0000x reference)
//
#include <hip/hip_runtime.h>

#define B_ROWS 32768
#define KCODES 4096
#define DLAT 128

// ---------------------------------------------------------------------------
// Generic 128x128-tile f32 GEMM, C = A[MxK] @ B[KxN] + bias[N]
// 256 threads, 8x8 micro-tile, BK=16. M,N must be multiples of 128.
// KTAIL=true handles K not a multiple of 16 (GEMM1: K=1420).
// ---------------------------------------------------------------------------
template<bool KTAIL>
__global__ __launch_bounds__(256)
void sgemm_f32(const float* __restrict__ A, const float* __restrict__ Bm,
               const float* __restrict__ bias, float* __restrict__ C,
               int M, int N, int K)
{
  __shared__ float As[16][128];
  __shared__ float Bs[16][128];
  const int tid = threadIdx.x;
  const int tr = tid >> 4;   // 0..15
  const int tc = tid & 15;   // 0..15
  const int m0 = blockIdx.y * 128;
  const int n0 = blockIdx.x * 128;

  float acc[8][8];
  #pragma unroll
  for (int i = 0; i < 8; ++i)
    #pragma unroll
    for (int j = 0; j < 8; ++j) acc[i][j] = 0.f;

  const int arow = tid >> 2;          // 0..63 (two passes, +64)
  const int acol = (tid & 3) << 2;    // 0,4,8,12
  const int brow = tid >> 5;          // 0..7 (two passes, +8)
  const int bcol = (tid & 31) << 2;   // 0..124

  const int nk = (K + 15) >> 4;
  for (int kt = 0; kt < nk; ++kt) {
    const int k0 = kt << 4;
    // stage A tile (128 rows x 16 k), transposed into As[k][m]
    #pragma unroll
    for (int p = 0; p < 2; ++p) {
      const int r = arow + p * 64;
      const float* src = A + (size_t)(m0 + r) * K + (k0 + acol);
      float4 v;
      if (!KTAIL || (k0 + acol + 3 < K)) {
        v = *reinterpret_cast<const float4*>(src);
      } else {
        v.x = (k0 + acol + 0 < K) ? src[0] : 0.f;
        v.y = (k0 + acol + 1 < K) ? src[1] : 0.f;
        v.z = (k0 + acol + 2 < K) ? src[2] : 0.f;
        v.w = (k0 + acol + 3 < K) ? src[3] : 0.f;
      }
      As[acol + 0][r] = v.x; As[acol + 1][r] = v.y;
      As[acol + 2][r] = v.z; As[acol + 3][r] = v.w;
    }
    // stage B tile (16 k x 128 n), natural layout
    #pragma unroll
    for (int p = 0; p < 2; ++p) {
      const int r = brow + p * 8;
      float4 v = make_float4(0.f, 0.f, 0.f, 0.f);
      if (!KTAIL || (k0 + r < K))
        v = *reinterpret_cast<const float4*>(Bm + (size_t)(k0 + r) * N + (n0 + bcol));
      *reinterpret_cast<float4*>(&Bs[r][bcol]) = v;
    }
    __syncthreads();
    #pragma unroll
    for (int kk = 0; kk < 16; ++kk) {
      float a[8], b[8];
      float4 t;
      t = *reinterpret_cast<const float4*>(&As[kk][tr * 8]);     a[0]=t.x;a[1]=t.y;a[2]=t.z;a[3]=t.w;
      t = *reinterpret_cast<const float4*>(&As[kk][tr * 8 + 4]); a[4]=t.x;a[5]=t.y;a[6]=t.z;a[7]=t.w;
      t = *reinterpret_cast<const float4*>(&Bs[kk][tc * 8]);     b[0]=t.x;b[1]=t.y;b[2]=t.z;b[3]=t.w;
      t = *reinterpret_cast<const float4*>(&Bs[kk][tc * 8 + 4]); b[4]=t.x;b[5]=t.y;b[6]=t.z;b[7]=t.w;
      #pragma unroll
      for (int i = 0; i < 8; ++i)
        #pragma unroll
        for (int j = 0; j < 8; ++j)
          acc[i][j] = fmaf(a[i], b[j], acc[i][j]);
    }
    __syncthreads();
  }
  #pragma unroll
  for (int i = 0; i < 8; ++i) {
    const int m = m0 + tr * 8 + i;
    float* dst = C + (size_t)m * N + (n0 + tc * 8);
    #pragma unroll
    for (int j = 0; j < 8; ++j)
      dst[j] = acc[i][j] + bias[n0 + tc * 8 + j];
  }
}

// ---------------------------------------------------------------------------
// Row-wise LayerNorm (+affine) + exact GELU (erf). One block (256 thr) per row.
// in/out may alias (each element read-then-written by the same thread).
// ---------------------------------------------------------------------------
__global__ __launch_bounds__(256)
void ln_gelu_kernel(const float* __restrict__ in, float* __restrict__ out,
                    const float* __restrict__ g, const float* __restrict__ be, int Wd)
{
  __shared__ float rs[4], rs2[4];
  const int row = blockIdx.x;
  const float* x = in + (size_t)row * Wd;
  float s = 0.f, s2 = 0.f;
  for (int c = threadIdx.x; c < Wd; c += 256) { float v = x[c]; s += v; s2 += v * v; }
  #pragma unroll
  for (int m = 32; m; m >>= 1) { s += __shfl_down(s, m); s2 += __shfl_down(s2, m); }
  const int lane = threadIdx.x & 63, wid = threadIdx.x >> 6;
  if (lane == 0) { rs[wid] = s; rs2[wid] = s2; }
  __syncthreads();
  if (threadIdx.x == 0) {
    float S = rs[0] + rs[1] + rs[2] + rs[3];
    float S2 = rs2[0] + rs2[1] + rs2[2] + rs2[3];
    float mean = S / Wd;
    float var = S2 / Wd - mean * mean;
    rs[0] = mean; rs2[0] = 1.0f / sqrtf(var + 1e-5f);
  }
  __syncthreads();
  const float mean = rs[0], inv = rs2[0];
  for (int c = threadIdx.x; c < Wd; c += 256) {
    float v = (x[c] - mean) * inv * g[c] + be[c];
    out[(size_t)row * Wd + c] = 0.5f * v * (1.f + erff(v * 0.70710678118654752f));
  }
}

// ---------------------------------------------------------------------------
// VQ scores + per-tile argmin. Tile: 128 rows x 128 codes, K = D = 128.
// score = ||e||^2 - 2 z.e  (per-row ||z||^2 dropped: argmin-invariant)
// ---------------------------------------------------------------------------
__global__ __launch_bounds__(256)
void vq_scores(const float* __restrict__ Z, const float* __restrict__ E,
               const float* __restrict__ e2, float* __restrict__ pval,
               int* __restrict__ pidx)
{
  __shared__ float As[16][128];
  __shared__ float Bs[16][128];
  const int tid = threadIdx.x;
  const int tr = tid >> 4, tc = tid & 15;
  const int m0 = blockIdx.y * 128, n0 = blockIdx.x * 128;

  float acc[8][8];
  #pragma unroll
  for (int i = 0; i < 8; ++i)
    #pragma unroll
    for (int j = 0; j < 8; ++j) acc[i][j] = 0.f;

  const int arow = tid >> 2;
  const int acol = (tid & 3) << 2;

  #pragma unroll
  for (int kt = 0; kt < 8; ++kt) {
    const int k0 = kt * 16;
    #pragma unroll
    for (int p = 0; p < 2; ++p) {
      const int r = arow + p * 64;
      float4 v = *reinterpret_cast<const float4*>(Z + (size_t)(m0 + r) * 128 + k0 + acol);
      As[acol + 0][r] = v.x; As[acol + 1][r] = v.y; As[acol + 2][r] = v.z; As[acol + 3][r] = v.w;
      float4 w = *reinterpret_cast<const float4*>(E + (size_t)(n0 + r) * 128 + k0 + acol);
      Bs[acol + 0][r] = w.x; Bs[acol + 1][r] = w.y; Bs[acol + 2][r] = w.z; Bs[acol + 3][r] = w.w;
    }
    __syncthreads();
    #pragma unroll
    for (int kk = 0; kk < 16; ++kk) {
      float a[8], b[8];
      float4 t;
      t = *reinterpret_cast<const float4*>(&As[kk][tr * 8]);     a[0]=t.x;a[1]=t.y;a[2]=t.z;a[3]=t.w;
      t = *reinterpret_cast<const float4*>(&As[kk][tr * 8 + 4]); a[4]=t.x;a[5]=t.y;a[6]=t.z;a[7]=t.w;
      t = *reinterpret_cast<const float4*>(&Bs[kk][tc * 8]);     b[0]=t.x;b[1]=t.y;b[2]=t.z;b[3]=t.w;
      t = *reinterpret_cast<const float4*>(&Bs[kk][tc * 8 + 4]); b[4]=t.x;b[5]=t.y;b[6]=t.z;b[7]=t.w;
      #pragma unroll
      for (int i = 0; i < 8; ++i)
        #pragma unroll
        for (int j = 0; j < 8; ++j)
          acc[i][j] = fmaf(a[i], b[j], acc[i][j]);
    }
    __syncthreads();
  }

  // per-row argmin over this 128-code tile
  #pragma unroll
  for (int i = 0; i < 8; ++i) {
    float bv = 3.4e38f; int bi = 0x7fffffff;
    #pragma unroll
    for (int j = 0; j < 8; ++j) {
      const int code = n0 + tc * 8 + j;
      float sc = e2[code] - 2.f * acc[i][j];
      if (sc < bv) { bv = sc; bi = code; }   // ascending j -> lowest idx on tie
    }
    #pragma unroll
    for (int m = 1; m < 16; m <<= 1) {
      float ov = __shfl_xor(bv, m);
      int oi = __shfl_xor(bi, m);
      if (ov < bv || (ov == bv && oi < bi)) { bv = ov; bi = oi; }
    }
    if (tc == 0) {
      const int row = m0 + tr * 8 + i;
      pval[(size_t)row * 32 + blockIdx.x] = bv;
      pidx[(size_t)row * 32 + blockIdx.x] = bi;
    }
  }
}

// final argmin across 32 code-blocks; histogram; index outputs
__global__ void vq_reduce(const float* __restrict__ pval, const int* __restrict__ pidx,
                          int* __restrict__ idxout, float* __restrict__ idxf,
                          int* __restrict__ counts)
{
  const int b = blockIdx.x * 256 + threadIdx.x;
  if (b >= B_ROWS) return;
  float best = 3.4e38f; int bi = 0;
  #pragma unroll
  for (int j = 0; j < 32; ++j) {           // ascending block -> lowest idx on tie
    float v = pval[(size_t)b * 32 + j];
    if (v < best) { best = v; bi = pidx[(size_t)b * 32 + j]; }
  }
  idxout[b] = bi;
  idxf[b] = (float)bi;
  atomicAdd(&counts[bi], 1);
}

// gather z_q -> z_q_st output; deterministic per-block commitment partial sums
__global__ __launch_bounds__(256)
void gather_commit(const int* __restrict__ idx, const float* __restrict__ E,
                   const float* __restrict__ ZE, float* __restrict__ ZQ,
                   float* __restrict__ cpart)
{
  __shared__ float red[4];
  const int b = blockIdx.x * 8 + (threadIdx.x >> 5);
  const int ch = threadIdx.x & 31;
  const int k = idx[b];
  float4 q = *reinterpret_cast<const float4*>(E + (size_t)k * 128 + ch * 4);
  float4 z = *reinterpret_cast<const float4*>(ZE + (size_t)b * 128 + ch * 4);
  *reinterpret_cast<float4*>(ZQ + (size_t)b * 128 + ch * 4) = q;
  float dx = q.x - z.x, dy = q.y - z.y, dz = q.z - z.z, dw = q.w - z.w;
  float s = dx * dx + dy * dy + dz * dz + dw * dw;
  #pragma unroll
  for (int m = 32; m; m >>= 1) s += __shfl_down(s, m);
  const int lane = threadIdx.x & 63, wid = threadIdx.x >> 6;
  if (lane == 0) red[wid] = s;
  __syncthreads();
  if (threadIdx.x == 0) cpart[blockIdx.x] = red[0] + red[1] + red[2] + red[3];
}

__global__ void e2_kernel(const float* __restrict__ E, float* __restrict__ e2)
{
  const int k = blockIdx.x * 256 + threadIdx.x;
  if (k >= KCODES) return;
  float s = 0.f;
  #pragma unroll 4
  for (int d = 0; d < 128; ++d) { float v = E[(size_t)k * 128 + d]; s += v * v; }
  e2[k] = s;
}

__global__ void zero_counts(int* counts)
{
  const int i = blockIdx.x * 256 + threadIdx.x;
  if (i < KCODES) counts[i] = 0;
}

__global__ void gelu_ew(float* __restrict__ p, int n)
{
  const int i = blockIdx.x * 256 + threadIdx.x;
  if (i < n) { float v = p[i]; p[i] = 0.5f * v * (1.f + erff(v * 0.70710678118654752f)); }
}

// tiny GEMM: V[Mx2] = T[Mx128] @ W6[128x2] + b6
__global__ void gemm_n2(const float* __restrict__ T, const float* __restrict__ W6,
                        const float* __restrict__ b6, float* __restrict__ V, int M)
{
  const int r = blockIdx.x * 256 + threadIdx.x;
  if (r >= M) return;
  float a0 = b6[0], a1 = b6[1];
  #pragma unroll 4
  for (int d = 0; d < 128; ++d) {
    float t = T[(size_t)r * 128 + d];
    a0 = fmaf(t, W6[d * 2 + 0], a0);
    a1 = fmaf(t, W6[d * 2 + 1], a1);
  }
  V[r * 2 + 0] = a0; V[r * 2 + 1] = a1;
}

__global__ void vel_gather(const int* __restrict__ idx, const float* __restrict__ V,
                           float* __restrict__ out)
{
  const int b = blockIdx.x * 256 + threadIdx.x;
  if (b >= B_ROWS) return;
  const int k = idx[b];
  out[b * 2 + 0] = V[k * 2 + 0];
  out[b * 2 + 1] = V[k * 2 + 1];
}

// deterministic scalar finish: commitment, perplexity, n_active
__global__ __launch_bounds__(256)
void stats_kernel(const float* __restrict__ cpart, const int* __restrict__ counts,
                  float* __restrict__ outs)
{
  __shared__ float sh[256];
  __shared__ float sh2[256];
  __shared__ int shi[256];
  const int t = threadIdx.x;
  float cs = 0.f;
  for (int i = t; i < 4096; i += 256) cs += cpart[i];
  float h = 0.f; int act = 0;
  for (int k = t; k < KCODES; k += 256) {
    float avg = counts[k] * (1.0f / 32768.0f);
    h += avg * logf(avg + 1e-10f);
    act += (avg > 0.001f) ? 1 : 0;
  }
  sh[t] = cs; sh2[t] = h; shi[t] = act;
  __syncthreads();
  for (int s = 128; s; s >>= 1) {
    if (t < s) { sh[t] += sh[t + s]; sh2[t] += sh2[t + s]; shi[t] += shi[t + s]; }
    __syncthreads();
  }
  if (t == 0) {
    outs[0] = 0.25f * sh[0] / (32768.0f * 128.0f);  // commitment
    outs[1] = expf(-sh2[0]);                        // perplexity
    outs[2] = (float)shi[0];                        // n_active
  }
}

extern "C" void kernel_launch(void* const* d_in, const int* in_sizes, int n_in,
                              void* d_out, int out_size, void* d_ws, size_t ws_size,
                              hipStream_t stream)
{
  const float* x   = (const float*)d_in[0];
  const float* W1  = (const float*)d_in[1];
  const float* b1  = (const float*)d_in[2];
  const float* g1  = (const float*)d_in[3];
  const float* be1 = (const float*)d_in[4];
  const float* W2  = (const float*)d_in[5];
  const float* b2  = (const float*)d_in[6];
  const float* g2  = (const float*)d_in[7];
  const float* be2 = (const float*)d_in[8];
  const float* W3  = (const float*)d_in[9];
  const float* b3  = (const float*)d_in[10];
  const float* emb = (const float*)d_in[11];
  const float* W4  = (const float*)d_in[12];
  const float* b4  = (const float*)d_in[13];
  const float* g3  = (const float*)d_in[14];
  const float* be3 = (const float*)d_in[15];
  const float* W5  = (const float*)d_in[16];
  const float* b5  = (const float*)d_in[17];
  const float* W6  = (const float*)d_in[18];
  const float* b6  = (const float*)d_in[19];

  float* out = (float*)d_out;
  // output layout (flat, return order)
  float* o_vel  = out;                                   // [B,2]
  float* o_ze   = out + 65536;                           // [B,128]
  float* o_zq   = out + 65536 + B_ROWS * 128;            // [B,128]
  float* o_idx  = out + 65536 + 2 * B_ROWS * 128;        // [B] (as float)
  float* o_scal = o_idx + B_ROWS;                        // 3 scalars

  float* ws = (float*)d_ws;
  // region 0..16.7M floats: h1 first, then (after h1 is dead) VQ partials + decoder bufs
  float* h1    = ws;                        // [B,512]  (live: steps 3-5)
  float* pval  = ws;                        // [B,32]   (live: steps 8-9)
  int*   pidx  = (int*)(ws + 1048576);      // [B,32]
  float* t1    = ws + 2097152;              // [4096,256]
  float* t2    = ws + 3145728;              // [4096,128]
  float* vv    = ws + 3670016;              // [4096,2]
  float* h2    = ws + 16777216;             // [B,256]
  float* e2    = ws + 25165824;             // [4096]
  int*   ind   = (int*)(ws + 25169920);     // [B]
  int*   cnt   = (int*)(ws + 25202688);     // [4096]
  float* cpart = ws + 25206784;             // [4096]

  // 1. init
  zero_counts<<<16, 256, 0, stream>>>(cnt);
  e2_kernel<<<16, 256, 0, stream>>>(emb, e2);

  // 2. encoder
  sgemm_f32<true><<<dim3(4, 256), 256, 0, stream>>>(x, W1, b1, h1, B_ROWS, 512, 1420);
  ln_gelu_kernel<<<B_ROWS, 256, 0, stream>>>(h1, h1, g1, be1, 512);
  sgemm_f32<false><<<dim3(2, 256), 256, 0, stream>>>(h1, W2, b2, h2, B_ROWS, 256, 512);
  ln_gelu_kernel<<<B_ROWS, 256, 0, stream>>>(h2, h2, g2, be2, 256);
  sgemm_f32<false><<<dim3(1, 256), 256, 0, stream>>>(h2, W3, b3, o_ze, B_ROWS, 128, 256);

  // 3. VQ: scores + argmin + gather + commitment partials + histogram
  vq_scores<<<dim3(32, 256), 256, 0, stream>>>(o_ze, emb, e2, pval, pidx);
  vq_reduce<<<128, 256, 0, stream>>>(pval, pidx, ind, o_idx, cnt);
  gather_commit<<<4096, 256, 0, stream>>>(ind, emb, o_ze, o_zq, cpart);

  // 4. decoder on the 4096 distinct codes, then gather
  sgemm_f32<false><<<dim3(2, 32), 256, 0, stream>>>(emb, W4, b4, t1, KCODES, 256, 128);
  ln_gelu_kernel<<<KCODES, 256, 0, stream>>>(t1, t1, g3, be3, 256);
  sgemm_f32<false><<<dim3(1, 32), 256, 0, stream>>>(t1, W5, b5, t2, KCODES, 128, 256);
  gelu_ew<<<(KCODES * 128 + 255) / 256, 256, 0, stream>>>(t2, KCODES * 128);
  gemm_n2<<<(KCODES + 255) / 256, 256, 0, stream>>>(t2, W6, b6, vv, KCODES);
  vel_gather<<<128, 256, 0, stream>>>(ind, vv, o_vel);

  // 5. scalars
  stats_kernel<<<1, 256, 0, stream>>>(cpart, cnt, o_scal);
}

// Round 2
// 1593.406 us; speedup vs baseline: 2.3298x; 2.3298x over previous
//
#include <hip/hip_runtime.h>

#define B_ROWS 32768
#define KCODES 4096
#define DLAT 128

// ---------------------------------------------------------------------------
// Generic 128x128-tile f32 GEMM, C = A[MxK] @ B[KxN] + bias[N]
// 256 threads, 8x8 micro-tile, BK=16. M,N must be multiples of 128.
// KTAIL=true handles K not a multiple of 16 (GEMM1: K=1420).
// ---------------------------------------------------------------------------
template<bool KTAIL>
__global__ __launch_bounds__(256)
void sgemm_f32(const float* __restrict__ A, const float* __restrict__ Bm,
               const float* __restrict__ bias, float* __restrict__ C,
               int M, int N, int K)
{
  __shared__ float As[16][128];
  __shared__ float Bs[16][128];
  const int tid = threadIdx.x;
  const int tr = tid >> 4;   // 0..15
  const int tc = tid & 15;   // 0..15
  const int m0 = blockIdx.y * 128;
  const int n0 = blockIdx.x * 128;

  float acc[8][8];
  #pragma unroll
  for (int i = 0; i < 8; ++i)
    #pragma unroll
    for (int j = 0; j < 8; ++j) acc[i][j] = 0.f;

  const int arow = tid >> 2;          // 0..63 (two passes, +64)
  const int acol = (tid & 3) << 2;    // 0,4,8,12
  const int brow = tid >> 5;          // 0..7 (two passes, +8)
  const int bcol = (tid & 31) << 2;   // 0..124

  const int nk = (K + 15) >> 4;
  for (int kt = 0; kt < nk; ++kt) {
    const int k0 = kt << 4;
    // stage A tile (128 rows x 16 k), transposed into As[k][m]
    #pragma unroll
    for (int p = 0; p < 2; ++p) {
      const int r = arow + p * 64;
      const float* src = A + (size_t)(m0 + r) * K + (k0 + acol);
      float4 v;
      if (!KTAIL || (k0 + acol + 3 < K)) {
        v = *reinterpret_cast<const float4*>(src);
      } else {
        v.x = (k0 + acol + 0 < K) ? src[0] : 0.f;
        v.y = (k0 + acol + 1 < K) ? src[1] : 0.f;
        v.z = (k0 + acol + 2 < K) ? src[2] : 0.f;
        v.w = (k0 + acol + 3 < K) ? src[3] : 0.f;
      }
      As[acol + 0][r] = v.x; As[acol + 1][r] = v.y;
      As[acol + 2][r] = v.z; As[acol + 3][r] = v.w;
    }
    // stage B tile (16 k x 128 n), natural layout
    #pragma unroll
    for (int p = 0; p < 2; ++p) {
      const int r = brow + p * 8;
      float4 v = make_float4(0.f, 0.f, 0.f, 0.f);
      if (!KTAIL || (k0 + r < K))
        v = *reinterpret_cast<const float4*>(Bm + (size_t)(k0 + r) * N + (n0 + bcol));
      *reinterpret_cast<float4*>(&Bs[r][bcol]) = v;
    }
    __syncthreads();
    #pragma unroll
    for (int kk = 0; kk < 16; ++kk) {
      float a[8], b[8];
      float4 t;
      t = *reinterpret_cast<const float4*>(&As[kk][tr * 8]);     a[0]=t.x;a[1]=t.y;a[2]=t.z;a[3]=t.w;
      t = *reinterpret_cast<const float4*>(&As[kk][tr * 8 + 4]); a[4]=t.x;a[5]=t.y;a[6]=t.z;a[7]=t.w;
      t = *reinterpret_cast<const float4*>(&Bs[kk][tc * 8]);     b[0]=t.x;b[1]=t.y;b[2]=t.z;b[3]=t.w;
      t = *reinterpret_cast<const float4*>(&Bs[kk][tc * 8 + 4]); b[4]=t.x;b[5]=t.y;b[6]=t.z;b[7]=t.w;
      #pragma unroll
      for (int i = 0; i < 8; ++i)
        #pragma unroll
        for (int j = 0; j < 8; ++j)
          acc[i][j] = fmaf(a[i], b[j], acc[i][j]);
    }
    __syncthreads();
  }
  #pragma unroll
  for (int i = 0; i < 8; ++i) {
    const int m = m0 + tr * 8 + i;
    float* dst = C + (size_t)m * N + (n0 + tc * 8);
    #pragma unroll
    for (int j = 0; j < 8; ++j)
      dst[j] = acc[i][j] + bias[n0 + tc * 8 + j];
  }
}

// ---------------------------------------------------------------------------
// Row-wise LayerNorm (+affine) + exact GELU (erf). One block (256 thr) per row.
// ---------------------------------------------------------------------------
__global__ __launch_bounds__(256)
void ln_gelu_kernel(const float* __restrict__ in, float* __restrict__ out,
                    const float* __restrict__ g, const float* __restrict__ be, int Wd)
{
  __shared__ float rs[4], rs2[4];
  const int row = blockIdx.x;
  const float* x = in + (size_t)row * Wd;
  float s = 0.f, s2 = 0.f;
  for (int c = threadIdx.x; c < Wd; c += 256) { float v = x[c]; s += v; s2 += v * v; }
  #pragma unroll
  for (int m = 32; m; m >>= 1) { s += __shfl_down(s, m); s2 += __shfl_down(s2, m); }
  const int lane = threadIdx.x & 63, wid = threadIdx.x >> 6;
  if (lane == 0) { rs[wid] = s; rs2[wid] = s2; }
  __syncthreads();
  if (threadIdx.x == 0) {
    float S = rs[0] + rs[1] + rs[2] + rs[3];
    float S2 = rs2[0] + rs2[1] + rs2[2] + rs2[3];
    float mean = S / Wd;
    float var = S2 / Wd - mean * mean;
    rs[0] = mean; rs2[0] = 1.0f / sqrtf(var + 1e-5f);
  }
  __syncthreads();
  const float mean = rs[0], inv = rs2[0];
  for (int c = threadIdx.x; c < Wd; c += 256) {
    float v = (x[c] - mean) * inv * g[c] + be[c];
    out[(size_t)row * Wd + c] = 0.5f * v * (1.f + erff(v * 0.70710678118654752f));
  }
}

// ---------------------------------------------------------------------------
// VQ streaming argmin. Block = 128 rows x 1024-code range (grid 4 x 256).
// Running per-row (best,idx) held in registers across 8 code-chunks of 128.
// score = ||e||^2 - 2 z.e  (per-row ||z||^2 dropped: argmin-invariant).
// kt loop is NOT unrolled (round-0 full unroll spilled: VGPR=256, 3.4GB scratch).
// ---------------------------------------------------------------------------
__global__ __launch_bounds__(256)
void vq_argmin(const float* __restrict__ Z, const float* __restrict__ E,
               const float* __restrict__ e2, float* __restrict__ pval,
               int* __restrict__ pidx)
{
  __shared__ float As[16][128];
  __shared__ float Bs[16][128];
  const int tid = threadIdx.x;
  const int tr = tid >> 4, tc = tid & 15;
  const int m0 = blockIdx.y * 128;
  const int split = blockIdx.x;            // 0..3, 1024 codes each

  float bv[8];
  int   bi[8];
  #pragma unroll
  for (int i = 0; i < 8; ++i) { bv[i] = 3.4e38f; bi[i] = 0x7fffffff; }

  const int arow = tid >> 2;
  const int acol = (tid & 3) << 2;

  #pragma unroll 1
  for (int ch = 0; ch < 8; ++ch) {
    const int n0 = split * 1024 + ch * 128;

    float acc[8][8];
    #pragma unroll
    for (int i = 0; i < 8; ++i)
      #pragma unroll
      for (int j = 0; j < 8; ++j) acc[i][j] = 0.f;

    #pragma unroll 1
    for (int kt = 0; kt < 8; ++kt) {
      const int k0 = kt * 16;
      #pragma unroll
      for (int p = 0; p < 2; ++p) {
        const int r = arow + p * 64;
        float4 v = *reinterpret_cast<const float4*>(Z + (size_t)(m0 + r) * 128 + k0 + acol);
        As[acol + 0][r] = v.x; As[acol + 1][r] = v.y; As[acol + 2][r] = v.z; As[acol + 3][r] = v.w;
        float4 w = *reinterpret_cast<const float4*>(E + (size_t)(n0 + r) * 128 + k0 + acol);
        Bs[acol + 0][r] = w.x; Bs[acol + 1][r] = w.y; Bs[acol + 2][r] = w.z; Bs[acol + 3][r] = w.w;
      }
      __syncthreads();
      #pragma unroll
      for (int kk = 0; kk < 16; ++kk) {
        float a[8], b[8];
        float4 t;
        t = *reinterpret_cast<const float4*>(&As[kk][tr * 8]);     a[0]=t.x;a[1]=t.y;a[2]=t.z;a[3]=t.w;
        t = *reinterpret_cast<const float4*>(&As[kk][tr * 8 + 4]); a[4]=t.x;a[5]=t.y;a[6]=t.z;a[7]=t.w;
        t = *reinterpret_cast<const float4*>(&Bs[kk][tc * 8]);     b[0]=t.x;b[1]=t.y;b[2]=t.z;b[3]=t.w;
        t = *reinterpret_cast<const float4*>(&Bs[kk][tc * 8 + 4]); b[4]=t.x;b[5]=t.y;b[6]=t.z;b[7]=t.w;
        #pragma unroll
        for (int i = 0; i < 8; ++i)
          #pragma unroll
          for (int j = 0; j < 8; ++j)
            acc[i][j] = fmaf(a[i], b[j], acc[i][j]);
      }
      __syncthreads();
    }

    // fold this chunk into the running per-row argmin (ascending code order)
    #pragma unroll
    for (int i = 0; i < 8; ++i) {
      #pragma unroll
      for (int j = 0; j < 8; ++j) {
        const int code = n0 + tc * 8 + j;
        float sc = e2[code] - 2.f * acc[i][j];
        if (sc < bv[i]) { bv[i] = sc; bi[i] = code; }   // strict <: lowest idx on tie
      }
    }
  }

  // cross-lane reduce over the 16 tc threads per row
  #pragma unroll
  for (int i = 0; i < 8; ++i) {
    float v = bv[i]; int ix = bi[i];
    #pragma unroll
    for (int m = 1; m < 16; m <<= 1) {
      float ov = __shfl_xor(v, m);
      int oi = __shfl_xor(ix, m);
      if (ov < v || (ov == v && oi < ix)) { v = ov; ix = oi; }
    }
    if (tc == 0) {
      const int row = m0 + tr * 8 + i;
      pval[(size_t)row * 4 + split] = v;
      pidx[(size_t)row * 4 + split] = ix;
    }
  }
}

// final argmin across 4 code-splits; histogram; index outputs
__global__ void vq_reduce(const float* __restrict__ pval, const int* __restrict__ pidx,
                          int* __restrict__ idxout, float* __restrict__ idxf,
                          int* __restrict__ counts)
{
  const int b = blockIdx.x * 256 + threadIdx.x;
  if (b >= B_ROWS) return;
  float best = 3.4e38f; int bi = 0;
  #pragma unroll
  for (int j = 0; j < 4; ++j) {            // ascending split -> lowest idx on tie
    float v = pval[(size_t)b * 4 + j];
    if (v < best) { best = v; bi = pidx[(size_t)b * 4 + j]; }
  }
  idxout[b] = bi;
  idxf[b] = (float)bi;
  atomicAdd(&counts[bi], 1);
}

// gather z_q -> z_q_st output; deterministic per-block commitment partial sums
__global__ __launch_bounds__(256)
void gather_commit(const int* __restrict__ idx, const float* __restrict__ E,
                   const float* __restrict__ ZE, float* __restrict__ ZQ,
                   float* __restrict__ cpart)
{
  __shared__ float red[4];
  const int b = blockIdx.x * 8 + (threadIdx.x >> 5);
  const int ch = threadIdx.x & 31;
  const int k = idx[b];
  float4 q = *reinterpret_cast<const float4*>(E + (size_t)k * 128 + ch * 4);
  float4 z = *reinterpret_cast<const float4*>(ZE + (size_t)b * 128 + ch * 4);
  *reinterpret_cast<float4*>(ZQ + (size_t)b * 128 + ch * 4) = q;
  float dx = q.x - z.x, dy = q.y - z.y, dz = q.z - z.z, dw = q.w - z.w;
  float s = dx * dx + dy * dy + dz * dz + dw * dw;
  #pragma unroll
  for (int m = 32; m; m >>= 1) s += __shfl_down(s, m);
  const int lane = threadIdx.x & 63, wid = threadIdx.x >> 6;
  if (lane == 0) red[wid] = s;
  __syncthreads();
  if (threadIdx.x == 0) cpart[blockIdx.x] = red[0] + red[1] + red[2] + red[3];
}

__global__ void e2_kernel(const float* __restrict__ E, float* __restrict__ e2)
{
  const int k = blockIdx.x * 256 + threadIdx.x;
  if (k >= KCODES) return;
  float s = 0.f;
  #pragma unroll 4
  for (int d = 0; d < 128; ++d) { float v = E[(size_t)k * 128 + d]; s += v * v; }
  e2[k] = s;
}

__global__ void zero_counts(int* counts)
{
  const int i = blockIdx.x * 256 + threadIdx.x;
  if (i < KCODES) counts[i] = 0;
}

__global__ void gelu_ew(float* __restrict__ p, int n)
{
  const int i = blockIdx.x * 256 + threadIdx.x;
  if (i < n) { float v = p[i]; p[i] = 0.5f * v * (1.f + erff(v * 0.70710678118654752f)); }
}

// tiny GEMM: V[Mx2] = T[Mx128] @ W6[128x2] + b6
__global__ void gemm_n2(const float* __restrict__ T, const float* __restrict__ W6,
                        const float* __restrict__ b6, float* __restrict__ V, int M)
{
  const int r = blockIdx.x * 256 + threadIdx.x;
  if (r >= M) return;
  float a0 = b6[0], a1 = b6[1];
  #pragma unroll 4
  for (int d = 0; d < 128; ++d) {
    float t = T[(size_t)r * 128 + d];
    a0 = fmaf(t, W6[d * 2 + 0], a0);
    a1 = fmaf(t, W6[d * 2 + 1], a1);
  }
  V[r * 2 + 0] = a0; V[r * 2 + 1] = a1;
}

__global__ void vel_gather(const int* __restrict__ idx, const float* __restrict__ V,
                           float* __restrict__ out)
{
  const int b = blockIdx.x * 256 + threadIdx.x;
  if (b >= B_ROWS) return;
  const int k = idx[b];
  out[b * 2 + 0] = V[k * 2 + 0];
  out[b * 2 + 1] = V[k * 2 + 1];
}

// deterministic scalar finish: commitment, perplexity, n_active
__global__ __launch_bounds__(256)
void stats_kernel(const float* __restrict__ cpart, const int* __restrict__ counts,
                  float* __restrict__ outs)
{
  __shared__ float sh[256];
  __shared__ float sh2[256];
  __shared__ int shi[256];
  const int t = threadIdx.x;
  float cs = 0.f;
  for (int i = t; i < 4096; i += 256) cs += cpart[i];
  float h = 0.f; int act = 0;
  for (int k = t; k < KCODES; k += 256) {
    float avg = counts[k] * (1.0f / 32768.0f);
    h += avg * logf(avg + 1e-10f);
    act += (avg > 0.001f) ? 1 : 0;
  }
  sh[t] = cs; sh2[t] = h; shi[t] = act;
  __syncthreads();
  for (int s = 128; s; s >>= 1) {
    if (t < s) { sh[t] += sh[t + s]; sh2[t] += sh2[t + s]; shi[t] += shi[t + s]; }
    __syncthreads();
  }
  if (t == 0) {
    outs[0] = 0.25f * sh[0] / (32768.0f * 128.0f);  // commitment
    outs[1] = expf(-sh2[0]);                        // perplexity
    outs[2] = (float)shi[0];                        // n_active
  }
}

extern "C" void kernel_launch(void* const* d_in, const int* in_sizes, int n_in,
                              void* d_out, int out_size, void* d_ws, size_t ws_size,
                              hipStream_t stream)
{
  const float* x   = (const float*)d_in[0];
  const float* W1  = (const float*)d_in[1];
  const float* b1  = (const float*)d_in[2];
  const float* g1  = (const float*)d_in[3];
  const float* be1 = (const float*)d_in[4];
  const float* W2  = (const float*)d_in[5];
  const float* b2  = (const float*)d_in[6];
  const float* g2  = (const float*)d_in[7];
  const float* be2 = (const float*)d_in[8];
  const float* W3  = (const float*)d_in[9];
  const float* b3  = (const float*)d_in[10];
  const float* emb = (const float*)d_in[11];
  const float* W4  = (const float*)d_in[12];
  const float* b4  = (const float*)d_in[13];
  const float* g3  = (const float*)d_in[14];
  const float* be3 = (const float*)d_in[15];
  const float* W5  = (const float*)d_in[16];
  const float* b5  = (const float*)d_in[17];
  const float* W6  = (const float*)d_in[18];
  const float* b6  = (const float*)d_in[19];

  float* out = (float*)d_out;
  // output layout (flat, return order)
  float* o_vel  = out;                                   // [B,2]
  float* o_ze   = out + 65536;                           // [B,128]
  float* o_zq   = out + 65536 + B_ROWS * 128;            // [B,128]
  float* o_idx  = out + 65536 + 2 * B_ROWS * 128;        // [B] (as float)
  float* o_scal = o_idx + B_ROWS;                        // 3 scalars

  float* ws = (float*)d_ws;
  float* h1    = ws;                        // [B,512]  (dead after GEMM2)
  float* pval  = ws;                        // [B,4]    (live: VQ only)
  int*   pidx  = (int*)(ws + 1048576);      // [B,4]
  float* t1    = ws + 2097152;              // [4096,256]
  float* t2    = ws + 3145728;              // [4096,128]
  float* vv    = ws + 3670016;              // [4096,2]
  float* h2    = ws + 16777216;             // [B,256]
  float* e2    = ws + 25165824;             // [4096]
  int*   ind   = (int*)(ws + 25169920);     // [B]
  int*   cnt   = (int*)(ws + 25202688);     // [4096]
  float* cpart = ws + 25206784;             // [4096]

  // 1. init
  zero_counts<<<16, 256, 0, stream>>>(cnt);
  e2_kernel<<<16, 256, 0, stream>>>(emb, e2);

  // 2. encoder
  sgemm_f32<true><<<dim3(4, 256), 256, 0, stream>>>(x, W1, b1, h1, B_ROWS, 512, 1420);
  ln_gelu_kernel<<<B_ROWS, 256, 0, stream>>>(h1, h1, g1, be1, 512);
  sgemm_f32<false><<<dim3(2, 256), 256, 0, stream>>>(h1, W2, b2, h2, B_ROWS, 256, 512);
  ln_gelu_kernel<<<B_ROWS, 256, 0, stream>>>(h2, h2, g2, be2, 256);
  sgemm_f32<false><<<dim3(1, 256), 256, 0, stream>>>(h2, W3, b3, o_ze, B_ROWS, 128, 256);

  // 3. VQ: streaming argmin + reduce + gather + commitment partials + histogram
  vq_argmin<<<dim3(4, 256), 256, 0, stream>>>(o_ze, emb, e2, pval, pidx);
  vq_reduce<<<128, 256, 0, stream>>>(pval, pidx, ind, o_idx, cnt);
  gather_commit<<<4096, 256, 0, stream>>>(ind, emb, o_ze, o_zq, cpart);

  // 4. decoder on the 4096 distinct codes, then gather
  sgemm_f32<false><<<dim3(2, 32), 256, 0, stream>>>(emb, W4, b4, t1, KCODES, 256, 128);
  ln_gelu_kernel<<<KCODES, 256, 0, stream>>>(t1, t1, g3, be3, 256);
  sgemm_f32<false><<<dim3(1, 32), 256, 0, stream>>>(t1, W5, b5, t2, KCODES, 128, 256);
  gelu_ew<<<(KCODES * 128 + 255) / 256, 256, 0, stream>>>(t2, KCODES * 128);
  gemm_n2<<<(KCODES + 255) / 256, 256, 0, stream>>>(t2, W6, b6, vv, KCODES);
  vel_gather<<<128, 256, 0, stream>>>(ind, vv, o_vel);

  // 5. scalars
  stats_kernel<<<1, 256, 0, stream>>>(cpart, cnt, o_scal);
}